// Round 1
// baseline (216.177 us; speedup 1.0000x reference)
//
#include <hip/hip_runtime.h>
#include <math.h>

#define GN 8192
#define BN 2
#define HN 256
#define WN 256
#define TILE 16
#define FRONT_K 8
#define EPS_T 1e-8f
#define ALPHA_T (1.0f / 255.0f)

// ---------------------------------------------------------------------------
// Kernel 1: per-batch depth sort (LDS bitonic on u64 (depth_bits<<32)|idx)
// + gather sorted SoA + precompute conservative screen bbox per gaussian.
// ---------------------------------------------------------------------------
__global__ __launch_bounds__(1024) void pgr_sort_gather(
    const float* __restrict__ means2d, const float* __restrict__ conics,
    const float* __restrict__ colors, const float* __restrict__ opac,
    const float* __restrict__ depths,
    float4* __restrict__ bbox, float4* __restrict__ dat0,
    float4* __restrict__ dat1, float* __restrict__ dat2)
{
    __shared__ unsigned long long key[GN];
    const int b = blockIdx.x;
    const int tid = threadIdx.x;
    const int NT = blockDim.x;  // 1024
    const float* dep = depths + b * GN;

    for (int i = tid; i < GN; i += NT)
        key[i] = ((unsigned long long)__float_as_uint(dep[i]) << 32) | (unsigned)i;
    __syncthreads();

    // bitonic sort ascending (depths are positive floats -> uint order ok;
    // index in low bits makes keys unique == stable argsort)
    for (unsigned k = 2; k <= GN; k <<= 1) {
        for (unsigned j = k >> 1; j > 0; j >>= 1) {
            for (unsigned i = tid; i < GN; i += (unsigned)NT) {
                unsigned ixj = i ^ j;
                if (ixj > i) {
                    unsigned long long a = key[i], bb = key[ixj];
                    bool up = ((i & k) == 0);
                    if (up ? (a > bb) : (a < bb)) { key[i] = bb; key[ixj] = a; }
                }
            }
            __syncthreads();
        }
    }

    // gather in sorted order + bbox precompute
    for (int i = tid; i < GN; i += NT) {
        int j = (int)(key[i] & 0xffffffffull);
        int src = b * GN + j;
        float mx = means2d[2 * src], my = means2d[2 * src + 1];
        float ca = conics[3 * src], cb = conics[3 * src + 1], cc = conics[3 * src + 2];
        float r = colors[3 * src], g2 = colors[3 * src + 1], b3 = colors[3 * src + 2];
        float op = opac[src];
        // alpha >= 1/255  <=>  sigma <= ln(255*op); conservative +1e-4 margin
        float s = (op > 0.f) ? (logf(255.0f * op) + 1e-4f) : -1.0f;
        float4 bx;
        if (s < 0.f) {
            bx = make_float4(3e9f, -3e9f, 3e9f, -3e9f);  // empty
        } else {
            float det = fmaxf(ca * cc - cb * cb, 1e-12f);
            float dxm = sqrtf(2.f * s * cc / det) + 0.02f;
            float dym = sqrtf(2.f * s * ca / det) + 0.02f;
            bx = make_float4(mx - dxm, mx + dxm, my - dym, my + dym);
        }
        int dst = b * GN + i;
        bbox[dst] = bx;
        dat0[dst] = make_float4(mx, my, ca, cb);
        dat1[dst] = make_float4(cc, op, r, g2);
        dat2[dst] = b3;
    }
}

// ---------------------------------------------------------------------------
// Kernel 2: tile rasterizer. 256 threads = 16x16 pixel tile. Per 256-gaussian
// chunk: bbox-vs-tile cull + order-preserving compaction into LDS, then each
// pixel composites survivors sequentially (exact reference semantics).
// ---------------------------------------------------------------------------
__global__ __launch_bounds__(256) void pgr_raster(
    const float4* __restrict__ bbox, const float4* __restrict__ dat0,
    const float4* __restrict__ dat1, const float* __restrict__ dat2,
    float* __restrict__ out)
{
    const int b = blockIdx.z;
    const int tx0 = blockIdx.x * TILE, ty0 = blockIdx.y * TILE;
    const int tid = threadIdx.x;
    const int lx = tid & 15, ly = tid >> 4;
    const float px = tx0 + lx + 0.5f, py = ty0 + ly + 0.5f;
    const float txmin = tx0 + 0.5f, txmax = tx0 + TILE - 0.5f;
    const float tymin = ty0 + 0.5f, tymax = ty0 + TILE - 0.5f;

    __shared__ float4 s_d0[256], s_d1[256];
    __shared__ float s_d2[256];
    __shared__ int s_idx[256];
    __shared__ int s_wcnt[4];

    float accR = 0.f, accG = 0.f, accB = 0.f, T = 1.f;
    int count = 0;
    bool done = false;
    const int bG = b * GN;

    for (int base = 0; base < GN; base += 256) {
        int g = base + tid;
        float4 bx = bbox[bG + g];
        bool pred = (bx.x <= txmax) && (bx.y >= txmin) &&
                    (bx.z <= tymax) && (bx.w >= tymin);

        unsigned long long m = __ballot(pred);
        int wave = tid >> 6, lane = tid & 63;
        if (lane == 0) s_wcnt[wave] = __popcll(m);
        int prefix = __popcll(m & ((1ull << lane) - 1ull));
        __syncthreads();
        int c0 = s_wcnt[0], c1 = s_wcnt[1], c2 = s_wcnt[2], c3 = s_wcnt[3];
        int woff = (wave > 0 ? c0 : 0) + (wave > 1 ? c1 : 0) + (wave > 2 ? c2 : 0);
        int total = c0 + c1 + c2 + c3;
        if (pred) s_idx[woff + prefix] = g;
        __syncthreads();
        if (tid < total) {
            int q = bG + s_idx[tid];
            s_d0[tid] = dat0[q];
            s_d1[tid] = dat1[q];
            s_d2[tid] = dat2[q];
        }
        __syncthreads();

        if (!done) {
            for (int i = 0; i < total; ++i) {
                float4 d0 = s_d0[i];
                float dx = __fsub_rn(px, d0.x);
                float dy = __fsub_rn(py, d0.y);
                // sigma = 0.5*((a*dx)*dx + (c*dy)*dy) + (b*dx)*dy  (numpy order, no FMA)
                float4 d1 = s_d1[i];
                float t1 = __fmul_rn(__fmul_rn(d0.z, dx), dx);
                float t2 = __fmul_rn(__fmul_rn(d1.x, dy), dy);
                float sigma = __fadd_rn(__fmul_rn(0.5f, __fadd_rn(t1, t2)),
                                        __fmul_rn(__fmul_rn(d0.w, dx), dy));
                if (sigma >= 0.f && sigma <= 5.55f) {  // e^-5.55 < 1/255 guaranteed
                    float alpha = fminf(__fmul_rn(d1.y, expf(-sigma)), 0.999f);
                    if (alpha >= ALPHA_T) {
                        if (T > EPS_T) {
                            float wgt = __fmul_rn(T, alpha);
                            accR += wgt * d1.z;
                            accG += wgt * d1.w;
                            accB += wgt * s_d2[i];
                        }
                        T = __fmul_rn(T, __fsub_rn(1.f, alpha));
                        count++;
                        if (count >= FRONT_K || T <= EPS_T) { done = true; break; }
                    }
                }
            }
        }
        if (__syncthreads_and((int)done)) break;
    }

    int o = ((b * HN + (ty0 + ly)) * WN + (tx0 + lx)) * 3;
    out[o] = accR;
    out[o + 1] = accG;
    out[o + 2] = accB;   // bg == 0, so output is accum only
}

extern "C" void kernel_launch(void* const* d_in, const int* in_sizes, int n_in,
                              void* d_out, int out_size, void* d_ws, size_t ws_size,
                              hipStream_t stream) {
    const float* means2d = (const float*)d_in[0];
    const float* conics  = (const float*)d_in[1];
    const float* colors  = (const float*)d_in[2];
    const float* opac    = (const float*)d_in[3];
    const float* depths  = (const float*)d_in[4];
    float* out = (float*)d_out;

    const int BG = BN * GN;
    float4* bbox = (float4*)d_ws;
    float4* dat0 = bbox + BG;
    float4* dat1 = dat0 + BG;
    float*  dat2 = (float*)(dat1 + BG);

    pgr_sort_gather<<<BN, 1024, 0, stream>>>(means2d, conics, colors, opac,
                                             depths, bbox, dat0, dat1, dat2);
    pgr_raster<<<dim3(WN / TILE, HN / TILE, BN), 256, 0, stream>>>(
        bbox, dat0, dat1, dat2, out);
}

// Round 2
// 156.337 us; speedup vs baseline: 1.3828x; 1.3828x over previous
//
#include <hip/hip_runtime.h>
#include <math.h>

#define GN 8192
#define BN 2
#define HN 256
#define WN 256
#define TILE 16
#define FRONT_K 8
#define EPS_T 1e-8f
#define ALPHA_T (1.0f / 255.0f)

// ---------------------------------------------------------------------------
// Kernel 1: fused rank-sort + gather + bbox precompute.
// rank_i = #{ j : key_j < key_i },  key = (depth_bits<<13) | idx  (unique,
// order-isomorphic to stable ascending argsort on depth). Each thread owns one
// gaussian, computes its rank against all 8192 keys (staged via LDS broadcast
// reads), then scatters its gathered SoA record to sorted position = rank.
// 64 blocks x 256 threads: no barrier-serialized bitonic, no inter-block sync.
// ---------------------------------------------------------------------------
#define RANK_TILE 2048

__global__ __launch_bounds__(256) void pgr_rank_gather(
    const float* __restrict__ means2d, const float* __restrict__ conics,
    const float* __restrict__ colors, const float* __restrict__ opac,
    const float* __restrict__ depths,
    float4* __restrict__ bbox, float4* __restrict__ dat0,
    float4* __restrict__ dat1, float* __restrict__ dat2)
{
    __shared__ __align__(16) unsigned long long s_key[RANK_TILE];
    const int b = blockIdx.x >> 5;                       // 32 blocks per batch
    const int i = ((blockIdx.x & 31) << 8) + threadIdx.x;
    const float* dep = depths + b * GN;

    const unsigned long long my =
        ((unsigned long long)__float_as_uint(dep[i]) << 13) | (unsigned)i;

    int rank = 0;
    for (int base = 0; base < GN; base += RANK_TILE) {
        for (int t = threadIdx.x; t < RANK_TILE; t += 256) {
            int j = base + t;
            s_key[t] = ((unsigned long long)__float_as_uint(dep[j]) << 13) | (unsigned)j;
        }
        __syncthreads();
        #pragma unroll 8
        for (int t = 0; t < RANK_TILE; t += 2) {
            ulonglong2 k2 = *reinterpret_cast<const ulonglong2*>(&s_key[t]);
            rank += (k2.x < my) + (k2.y < my);
        }
        __syncthreads();
    }

    // gather this gaussian's data + bbox, scatter to sorted slot = rank
    int src = b * GN + i;
    float mx = means2d[2 * src], my2 = means2d[2 * src + 1];
    float ca = conics[3 * src], cb = conics[3 * src + 1], cc = conics[3 * src + 2];
    float r = colors[3 * src], g2 = colors[3 * src + 1], b3 = colors[3 * src + 2];
    float op = opac[src];
    // alpha >= 1/255  <=>  sigma <= ln(255*op); conservative +1e-4 margin
    float s = (op > 0.f) ? (logf(255.0f * op) + 1e-4f) : -1.0f;
    float4 bx;
    if (s < 0.f) {
        bx = make_float4(3e9f, -3e9f, 3e9f, -3e9f);      // empty
    } else {
        float det = fmaxf(ca * cc - cb * cb, 1e-12f);
        float dxm = sqrtf(2.f * s * cc / det) + 0.02f;
        float dym = sqrtf(2.f * s * ca / det) + 0.02f;
        bx = make_float4(mx - dxm, mx + dxm, my2 - dym, my2 + dym);
    }
    int dst = b * GN + rank;
    bbox[dst] = bx;
    dat0[dst] = make_float4(mx, my2, ca, cb);
    dat1[dst] = make_float4(cc, op, r, g2);
    dat2[dst] = b3;
}

// ---------------------------------------------------------------------------
// Kernel 2: tile rasterizer. 256 threads = 16x16 pixel tile. Per 256-gaussian
// chunk: bbox-vs-tile cull + order-preserving compaction into LDS, then each
// pixel composites survivors sequentially (exact reference semantics).
// ---------------------------------------------------------------------------
__global__ __launch_bounds__(256) void pgr_raster(
    const float4* __restrict__ bbox, const float4* __restrict__ dat0,
    const float4* __restrict__ dat1, const float* __restrict__ dat2,
    float* __restrict__ out)
{
    const int b = blockIdx.z;
    const int tx0 = blockIdx.x * TILE, ty0 = blockIdx.y * TILE;
    const int tid = threadIdx.x;
    const int lx = tid & 15, ly = tid >> 4;
    const float px = tx0 + lx + 0.5f, py = ty0 + ly + 0.5f;
    const float txmin = tx0 + 0.5f, txmax = tx0 + TILE - 0.5f;
    const float tymin = ty0 + 0.5f, tymax = ty0 + TILE - 0.5f;

    __shared__ float4 s_d0[256], s_d1[256];
    __shared__ float s_d2[256];
    __shared__ int s_idx[256];
    __shared__ int s_wcnt[4];

    float accR = 0.f, accG = 0.f, accB = 0.f, T = 1.f;
    int count = 0;
    bool done = false;
    const int bG = b * GN;

    for (int base = 0; base < GN; base += 256) {
        int g = base + tid;
        float4 bx = bbox[bG + g];
        bool pred = (bx.x <= txmax) && (bx.y >= txmin) &&
                    (bx.z <= tymax) && (bx.w >= tymin);

        unsigned long long m = __ballot(pred);
        int wave = tid >> 6, lane = tid & 63;
        if (lane == 0) s_wcnt[wave] = __popcll(m);
        int prefix = __popcll(m & ((1ull << lane) - 1ull));
        __syncthreads();
        int c0 = s_wcnt[0], c1 = s_wcnt[1], c2 = s_wcnt[2], c3 = s_wcnt[3];
        int woff = (wave > 0 ? c0 : 0) + (wave > 1 ? c1 : 0) + (wave > 2 ? c2 : 0);
        int total = c0 + c1 + c2 + c3;
        if (pred) s_idx[woff + prefix] = g;
        __syncthreads();
        if (tid < total) {
            int q = bG + s_idx[tid];
            s_d0[tid] = dat0[q];
            s_d1[tid] = dat1[q];
            s_d2[tid] = dat2[q];
        }
        __syncthreads();

        if (!done) {
            for (int i = 0; i < total; ++i) {
                float4 d0 = s_d0[i];
                float dx = __fsub_rn(px, d0.x);
                float dy = __fsub_rn(py, d0.y);
                // sigma = 0.5*((a*dx)*dx + (c*dy)*dy) + (b*dx)*dy  (numpy order, no FMA)
                float4 d1 = s_d1[i];
                float t1 = __fmul_rn(__fmul_rn(d0.z, dx), dx);
                float t2 = __fmul_rn(__fmul_rn(d1.x, dy), dy);
                float sigma = __fadd_rn(__fmul_rn(0.5f, __fadd_rn(t1, t2)),
                                        __fmul_rn(__fmul_rn(d0.w, dx), dy));
                if (sigma >= 0.f && sigma <= 5.55f) {  // e^-5.55 < 1/255 guaranteed
                    float alpha = fminf(__fmul_rn(d1.y, expf(-sigma)), 0.999f);
                    if (alpha >= ALPHA_T) {
                        if (T > EPS_T) {
                            float wgt = __fmul_rn(T, alpha);
                            accR += wgt * d1.z;
                            accG += wgt * d1.w;
                            accB += wgt * s_d2[i];
                        }
                        T = __fmul_rn(T, __fsub_rn(1.f, alpha));
                        count++;
                        if (count >= FRONT_K || T <= EPS_T) { done = true; break; }
                    }
                }
            }
        }
        if (__syncthreads_and((int)done)) break;
    }

    int o = ((b * HN + (ty0 + ly)) * WN + (tx0 + lx)) * 3;
    out[o] = accR;
    out[o + 1] = accG;
    out[o + 2] = accB;   // bg == 0, so output is accum only
}

extern "C" void kernel_launch(void* const* d_in, const int* in_sizes, int n_in,
                              void* d_out, int out_size, void* d_ws, size_t ws_size,
                              hipStream_t stream) {
    const float* means2d = (const float*)d_in[0];
    const float* conics  = (const float*)d_in[1];
    const float* colors  = (const float*)d_in[2];
    const float* opac    = (const float*)d_in[3];
    const float* depths  = (const float*)d_in[4];
    float* out = (float*)d_out;

    const int BG = BN * GN;
    float4* bbox = (float4*)d_ws;
    float4* dat0 = bbox + BG;
    float4* dat1 = dat0 + BG;
    float*  dat2 = (float*)(dat1 + BG);

    pgr_rank_gather<<<BN * 32, 256, 0, stream>>>(means2d, conics, colors, opac,
                                                 depths, bbox, dat0, dat1, dat2);
    pgr_raster<<<dim3(WN / TILE, HN / TILE, BN), 256, 0, stream>>>(
        bbox, dat0, dat1, dat2, out);
}

// Round 3
// 85.058 us; speedup vs baseline: 2.5415x; 1.8380x over previous
//
#include <hip/hip_runtime.h>
#include <math.h>

#define GN 8192
#define BN 2
#define HN 256
#define WN 256
#define TILE 16
#define FRONT_K 8
#define EPS_T 1e-8f
#define ALPHA_T (1.0f / 255.0f)

// ---------------------------------------------------------------------------
// Kernel 1: fused rank-sort + gather + bbox precompute.
// rank_i = #{ j : key_j < key_i }, key = (depth_bits<<13) | idx (unique,
// order-isomorphic to stable ascending argsort on positive-float depth).
// 8 lanes per gaussian each count a 1/8 interleaved slice of the keys
// (staged through LDS in 16 KiB tiles), then __shfl_xor-reduce. 512 blocks
// x 256 threads = 8 waves/CU -> latency hidden (r2 fix: was 1 wave/CU).
// ---------------------------------------------------------------------------
#define RTILE 2048

__global__ __launch_bounds__(256) void pgr_rank_gather(
    const float* __restrict__ means2d, const float* __restrict__ conics,
    const float* __restrict__ colors, const float* __restrict__ opac,
    const float* __restrict__ depths,
    float4* __restrict__ bbox, float4* __restrict__ dat0,
    float4* __restrict__ dat1, float* __restrict__ dat2)
{
    __shared__ __align__(16) unsigned long long s_key[RTILE];
    const int b = blockIdx.x >> 8;                       // 256 blocks per batch
    const int i = ((blockIdx.x & 255) << 5) + (threadIdx.x >> 3);
    const int p = threadIdx.x & 7;                       // partial-lane id
    const float* dep = depths + b * GN;

    const unsigned long long my =
        ((unsigned long long)__float_as_uint(dep[i]) << 13) | (unsigned)i;

    int rank = 0;
    for (int base = 0; base < GN; base += RTILE) {
        for (int t = threadIdx.x; t < RTILE; t += 256) {
            int j = base + t;
            s_key[t] = ((unsigned long long)__float_as_uint(dep[j]) << 13) | (unsigned)j;
        }
        __syncthreads();
        // lane p reads keys {16t + 2p, 16t + 2p + 1}: 8 lanes cover 32 banks,
        // remaining 7 groups broadcast the same addresses -> conflict-free.
        #pragma unroll 8
        for (int t = 0; t < RTILE / 16; ++t) {
            ulonglong2 k2 = *reinterpret_cast<const ulonglong2*>(&s_key[t * 16 + 2 * p]);
            rank += (k2.x < my) + (k2.y < my);
        }
        __syncthreads();
    }
    // sum the 8 partials (lanes p=0..7 of this gaussian's group)
    rank += __shfl_xor(rank, 1, 64);
    rank += __shfl_xor(rank, 2, 64);
    rank += __shfl_xor(rank, 4, 64);

    if (p == 0) {
        // gather this gaussian's data + bbox, scatter to sorted slot = rank
        int src = b * GN + i;
        float mx = means2d[2 * src], my2 = means2d[2 * src + 1];
        float ca = conics[3 * src], cb = conics[3 * src + 1], cc = conics[3 * src + 2];
        float r = colors[3 * src], g2 = colors[3 * src + 1], b3 = colors[3 * src + 2];
        float op = opac[src];
        // alpha >= 1/255  <=>  sigma <= ln(255*op); conservative +1e-4 margin
        float s = (op > 0.f) ? (logf(255.0f * op) + 1e-4f) : -1.0f;
        float4 bx;
        if (s < 0.f) {
            bx = make_float4(3e9f, -3e9f, 3e9f, -3e9f);  // empty
        } else {
            float det = fmaxf(ca * cc - cb * cb, 1e-12f);
            float dxm = sqrtf(2.f * s * cc / det) + 0.02f;
            float dym = sqrtf(2.f * s * ca / det) + 0.02f;
            bx = make_float4(mx - dxm, mx + dxm, my2 - dym, my2 + dym);
        }
        int dst = b * GN + rank;
        bbox[dst] = bx;
        dat0[dst] = make_float4(mx, my2, ca, cb);
        dat1[dst] = make_float4(cc, op, r, g2);
        dat2[dst] = b3;
    }
}

// ---------------------------------------------------------------------------
// Kernel 2: tile rasterizer. 256 threads = 16x16 pixel tile. Per 256-gaussian
// chunk: bbox-vs-tile cull, survivors self-stage into per-wave ordered LDS
// segments (depth order preserved: wave w's segment = gaussians [64w,64w+64)),
// then each pixel composites survivors sequentially (exact ref semantics).
// 2 barriers per chunk (was 4); next chunk's bbox prefetched pre-barrier.
// ---------------------------------------------------------------------------
__global__ __launch_bounds__(256) void pgr_raster(
    const float4* __restrict__ bbox, const float4* __restrict__ dat0,
    const float4* __restrict__ dat1, const float* __restrict__ dat2,
    float* __restrict__ out)
{
    const int b = blockIdx.z;
    const int tx0 = blockIdx.x * TILE, ty0 = blockIdx.y * TILE;
    const int tid = threadIdx.x;
    const int lx = tid & 15, ly = tid >> 4;
    const float px = tx0 + lx + 0.5f, py = ty0 + ly + 0.5f;
    const float txmin = tx0 + 0.5f, txmax = tx0 + TILE - 0.5f;
    const float tymin = ty0 + 0.5f, tymax = ty0 + TILE - 0.5f;

    __shared__ float4 s_d0[256], s_d1[256];
    __shared__ float s_d2[256];
    __shared__ int s_wcnt[4];

    float accR = 0.f, accG = 0.f, accB = 0.f, T = 1.f;
    int count = 0;
    bool done = false;
    const int bG = b * GN;
    const int wave = tid >> 6, lane = tid & 63;

    float4 bx = bbox[bG + tid];                          // chunk 0 prefetch

    for (int base = 0; base < GN; base += 256) {
        int g = base + tid;
        bool pred = (bx.x <= txmax) && (bx.y >= txmin) &&
                    (bx.z <= tymax) && (bx.w >= tymin);

        unsigned long long m = __ballot(pred);
        if (lane == 0) s_wcnt[wave] = __popcll(m);
        if (pred) {
            int slot = (wave << 6) + __popcll(m & ((1ull << lane) - 1ull));
            int q = bG + g;
            s_d0[slot] = dat0[q];
            s_d1[slot] = dat1[q];
            s_d2[slot] = dat2[q];
        }
        if (base + 256 < GN) bx = bbox[bG + base + 256 + tid];  // prefetch next
        __syncthreads();

        if (!done) {
            for (int w = 0; w < 4 && !done; ++w) {
                int cw = s_wcnt[w];
                int s0 = w << 6;
                for (int i = 0; i < cw; ++i) {
                    float4 d0 = s_d0[s0 + i];
                    float dx = __fsub_rn(px, d0.x);
                    float dy = __fsub_rn(py, d0.y);
                    // sigma = 0.5*((a*dx)*dx + (c*dy)*dy) + (b*dx)*dy (numpy order)
                    float4 d1 = s_d1[s0 + i];
                    float t1 = __fmul_rn(__fmul_rn(d0.z, dx), dx);
                    float t2 = __fmul_rn(__fmul_rn(d1.x, dy), dy);
                    float sigma = __fadd_rn(__fmul_rn(0.5f, __fadd_rn(t1, t2)),
                                            __fmul_rn(__fmul_rn(d0.w, dx), dy));
                    if (sigma >= 0.f && sigma <= 5.55f) {  // e^-5.55 < 1/255
                        float alpha = fminf(__fmul_rn(d1.y, expf(-sigma)), 0.999f);
                        if (alpha >= ALPHA_T) {
                            if (T > EPS_T) {
                                float wgt = __fmul_rn(T, alpha);
                                accR += wgt * d1.z;
                                accG += wgt * d1.w;
                                accB += wgt * s_d2[s0 + i];
                            }
                            T = __fmul_rn(T, __fsub_rn(1.f, alpha));
                            count++;
                            if (count >= FRONT_K || T <= EPS_T) { done = true; break; }
                        }
                    }
                }
            }
        }
        if (__syncthreads_and((int)done)) break;
    }

    int o = ((b * HN + (ty0 + ly)) * WN + (tx0 + lx)) * 3;
    out[o] = accR;
    out[o + 1] = accG;
    out[o + 2] = accB;   // bg == 0, so output is accum only
}

extern "C" void kernel_launch(void* const* d_in, const int* in_sizes, int n_in,
                              void* d_out, int out_size, void* d_ws, size_t ws_size,
                              hipStream_t stream) {
    const float* means2d = (const float*)d_in[0];
    const float* conics  = (const float*)d_in[1];
    const float* colors  = (const float*)d_in[2];
    const float* opac    = (const float*)d_in[3];
    const float* depths  = (const float*)d_in[4];
    float* out = (float*)d_out;

    const int BG = BN * GN;
    float4* bbox = (float4*)d_ws;
    float4* dat0 = bbox + BG;
    float4* dat1 = dat0 + BG;
    float*  dat2 = (float*)(dat1 + BG);

    pgr_rank_gather<<<BN * 256, 256, 0, stream>>>(means2d, conics, colors, opac,
                                                  depths, bbox, dat0, dat1, dat2);
    pgr_raster<<<dim3(WN / TILE, HN / TILE, BN), 256, 0, stream>>>(
        bbox, dat0, dat1, dat2, out);
}

// Round 4
// 83.851 us; speedup vs baseline: 2.5781x; 1.0144x over previous
//
#include <hip/hip_runtime.h>
#include <math.h>

#define GN 8192
#define BN 2
#define HN 256
#define WN 256
#define FRONT_K 8
#define EPS_T 1e-8f
#define ALPHA_T (1.0f / 255.0f)

// ---------------------------------------------------------------------------
// Kernel 1: fused rank-sort + gather + bbox precompute.
// rank_i = #{ j : key_j < key_i }, key = (depth_bits<<13) | idx (unique,
// order-isomorphic to stable ascending argsort on positive-float depth;
// 13 bits exactly covers idx<8192). 16 lanes per gaussian each count a 1/16
// interleaved slice of the keys (LDS-staged tiles), then __shfl_xor-reduce.
// 1024 blocks x 256 thr = 16 waves/CU (r3 fix: was 8 waves/CU, latency-bound).
// ---------------------------------------------------------------------------
#define RTILE 2048

__global__ __launch_bounds__(256) void pgr_rank_gather(
    const float* __restrict__ means2d, const float* __restrict__ conics,
    const float* __restrict__ colors, const float* __restrict__ opac,
    const float* __restrict__ depths,
    float4* __restrict__ bbox, float4* __restrict__ dat0,
    float4* __restrict__ dat1, float* __restrict__ dat2)
{
    __shared__ __align__(16) unsigned long long s_key[RTILE];
    const int b = blockIdx.x >> 9;                       // 512 blocks per batch
    const int i = ((blockIdx.x & 511) << 4) + (threadIdx.x >> 4);
    const int p = threadIdx.x & 15;                      // partial-lane id
    const float* dep = depths + b * GN;

    const unsigned long long my =
        ((unsigned long long)__float_as_uint(dep[i]) << 13) | (unsigned)i;

    int rank = 0;
    for (int base = 0; base < GN; base += RTILE) {
        for (int t = threadIdx.x; t < RTILE; t += 256) {
            int j = base + t;
            s_key[t] = ((unsigned long long)__float_as_uint(dep[j]) << 13) | (unsigned)j;
        }
        __syncthreads();
        // lane p reads keys {32t+2p, 32t+2p+1}: 16 lanes x 16B = 2-way bank
        // aliasing (free per m136); other lane-groups broadcast same addrs.
        #pragma unroll 8
        for (int t = 0; t < RTILE / 32; ++t) {
            ulonglong2 k2 = *reinterpret_cast<const ulonglong2*>(&s_key[t * 32 + 2 * p]);
            rank += (k2.x < my) + (k2.y < my);
        }
        __syncthreads();
    }
    // sum the 16 partials (lanes p=0..15 of this gaussian's group)
    rank += __shfl_xor(rank, 1, 64);
    rank += __shfl_xor(rank, 2, 64);
    rank += __shfl_xor(rank, 4, 64);
    rank += __shfl_xor(rank, 8, 64);

    if (p == 0) {
        // gather this gaussian's data + bbox, scatter to sorted slot = rank
        int src = b * GN + i;
        float mx = means2d[2 * src], my2 = means2d[2 * src + 1];
        float ca = conics[3 * src], cb = conics[3 * src + 1], cc = conics[3 * src + 2];
        float r = colors[3 * src], g2 = colors[3 * src + 1], b3 = colors[3 * src + 2];
        float op = opac[src];
        // alpha >= 1/255  <=>  sigma <= ln(255*op); conservative +1e-4 margin
        float s = (op > 0.f) ? (logf(255.0f * op) + 1e-4f) : -1.0f;
        float4 bx;
        if (s < 0.f) {
            bx = make_float4(3e9f, -3e9f, 3e9f, -3e9f);  // empty
        } else {
            float det = fmaxf(ca * cc - cb * cb, 1e-12f);
            float dxm = sqrtf(2.f * s * cc / det) + 0.02f;
            float dym = sqrtf(2.f * s * ca / det) + 0.02f;
            bx = make_float4(mx - dxm, mx + dxm, my2 - dym, my2 + dym);
        }
        int dst = b * GN + rank;
        bbox[dst] = bx;
        dat0[dst] = make_float4(mx, my2, ca, cb);
        dat1[dst] = make_float4(cc, op, r, g2);
        dat2[dst] = b3;
    }
}

// ---------------------------------------------------------------------------
// Kernel 2: tile rasterizer. 64 threads = one wave = one 8x8 pixel tile
// (r3: was 256thr/16x16 — 1-wave blocks make barriers ~free, finer early
// exit, ~2.5x fewer survivors/tile). Per 64-gaussian chunk: bbox cull,
// ballot-compact survivors into LDS (order preserved), composite in 4-wide
// batches: phase 1 = loads+sigma+exp with full ILP, phase 2 = serial blend.
// ---------------------------------------------------------------------------
__global__ __launch_bounds__(64) void pgr_raster(
    const float4* __restrict__ bbox, const float4* __restrict__ dat0,
    const float4* __restrict__ dat1, const float* __restrict__ dat2,
    float* __restrict__ out)
{
    const int b = blockIdx.z;
    const int tx0 = blockIdx.x * 8, ty0 = blockIdx.y * 8;
    const int tid = threadIdx.x;
    const int lx = tid & 7, ly = tid >> 3;
    const float px = tx0 + lx + 0.5f, py = ty0 + ly + 0.5f;
    const float txmin = tx0 + 0.5f, txmax = tx0 + 7.5f;
    const float tymin = ty0 + 0.5f, tymax = ty0 + 7.5f;

    __shared__ float4 s_d0[64], s_d1[64];
    __shared__ float s_d2[64];

    float accR = 0.f, accG = 0.f, accB = 0.f, T = 1.f;
    int count = 0;
    bool done = false;
    const int bG = b * GN;

    float4 bx = bbox[bG + tid];                          // chunk 0 prefetch

    for (int base = 0; base < GN; base += 64) {
        bool pred = (bx.x <= txmax) && (bx.y >= txmin) &&
                    (bx.z <= tymax) && (bx.w >= tymin);
        unsigned long long m = __ballot(pred);
        int cnt = __popcll(m);
        if (pred) {
            int slot = __popcll(m & ((1ull << tid) - 1ull));
            int q = bG + base + tid;
            s_d0[slot] = dat0[q];
            s_d1[slot] = dat1[q];
            s_d2[slot] = dat2[q];
        }
        if (base + 64 < GN) bx = bbox[bG + base + 64 + tid];  // prefetch next
        __syncthreads();   // 1 wave: compiles to cheap barrier + waitcnt

        if (cnt && !done) {
            for (int i0 = 0; i0 < cnt && !done; i0 += 4) {
                float alpha[4], colR[4], colG[4], colB[4];
                bool valid[4];
                // phase 1: independent loads + sigma + exp (ILP hides latency)
                #pragma unroll
                for (int k = 0; k < 4; ++k) {
                    int idx = i0 + k;
                    bool act = (idx < cnt) && !done;
                    int ii = act ? idx : i0;             // clamped, discarded
                    float4 d0 = s_d0[ii];
                    float4 d1 = s_d1[ii];
                    float dx = __fsub_rn(px, d0.x);
                    float dy = __fsub_rn(py, d0.y);
                    // sigma = 0.5*((a*dx)*dx + (c*dy)*dy) + (b*dx)*dy (numpy order)
                    float t1 = __fmul_rn(__fmul_rn(d0.z, dx), dx);
                    float t2 = __fmul_rn(__fmul_rn(d1.x, dy), dy);
                    float sigma = __fadd_rn(__fmul_rn(0.5f, __fadd_rn(t1, t2)),
                                            __fmul_rn(__fmul_rn(d0.w, dx), dy));
                    bool v = act && sigma >= 0.f && sigma <= 5.55f;  // e^-5.55 < 1/255
                    float al = v ? fminf(__fmul_rn(d1.y, expf(-sigma)), 0.999f) : 0.f;
                    valid[k] = v && (al >= ALPHA_T);
                    alpha[k] = al;
                    colR[k] = d1.z; colG[k] = d1.w; colB[k] = s_d2[ii];
                }
                // phase 2: serial front-to-back blend (exact ref semantics)
                #pragma unroll
                for (int k = 0; k < 4; ++k) {
                    if (valid[k] && !done) {
                        float al = alpha[k];
                        if (T > EPS_T) {
                            float w = __fmul_rn(T, al);
                            accR += w * colR[k];
                            accG += w * colG[k];
                            accB += w * colB[k];
                        }
                        T = __fmul_rn(T, __fsub_rn(1.f, al));
                        count++;
                        if (count >= FRONT_K || T <= EPS_T) done = true;
                    }
                }
            }
        }
        if (__all((int)done)) break;
        __builtin_amdgcn_wave_barrier();   // keep compiler from crossing iters
    }

    int o = ((b * HN + (ty0 + ly)) * WN + (tx0 + lx)) * 3;
    out[o] = accR;
    out[o + 1] = accG;
    out[o + 2] = accB;   // bg == 0, so output is accum only
}

extern "C" void kernel_launch(void* const* d_in, const int* in_sizes, int n_in,
                              void* d_out, int out_size, void* d_ws, size_t ws_size,
                              hipStream_t stream) {
    const float* means2d = (const float*)d_in[0];
    const float* conics  = (const float*)d_in[1];
    const float* colors  = (const float*)d_in[2];
    const float* opac    = (const float*)d_in[3];
    const float* depths  = (const float*)d_in[4];
    float* out = (float*)d_out;

    const int BG = BN * GN;
    float4* bbox = (float4*)d_ws;
    float4* dat0 = bbox + BG;
    float4* dat1 = dat0 + BG;
    float*  dat2 = (float*)(dat1 + BG);

    pgr_rank_gather<<<BN * 512, 256, 0, stream>>>(means2d, conics, colors, opac,
                                                  depths, bbox, dat0, dat1, dat2);
    pgr_raster<<<dim3(WN / 8, HN / 8, BN), 64, 0, stream>>>(
        bbox, dat0, dat1, dat2, out);
}

// Round 5
// 56.691 us; speedup vs baseline: 3.8133x; 1.4791x over previous
//
#include <hip/hip_runtime.h>
#include <math.h>

#define GN 8192
#define BN 2
#define HN 256
#define WN 256
#define FRONT_K 8
#define EPS_T 1e-8f
#define ALPHA_T (1.0f / 255.0f)
#define TDIM 32                 // 32x32 tiles of 8x8 px per batch
#define NTILE (TDIM * TDIM)
#define CAP 192                 // per-tile list capacity (mean ~48, ~20 sigma)

// ---------------------------------------------------------------------------
// Kernel 1: prep + binning. One thread per (batch, gaussian):
//  - repack SoA records (ORIGINAL order; no global sort needed anymore)
//  - conservative bbox (alpha>=1/255 <=> sigma<=ln(255*op)) -> tile rect
//  - atomicAdd-append orig index to each covered tile's list (order-free:
//    the raster sorts each tiny list by (depth,idx) key deterministically)
// ---------------------------------------------------------------------------
__global__ __launch_bounds__(256) void pgr_prep(
    const float* __restrict__ means2d, const float* __restrict__ conics,
    const float* __restrict__ colors, const float* __restrict__ opac,
    float4* __restrict__ dat0, float4* __restrict__ dat1,
    float* __restrict__ dat2, unsigned* __restrict__ cur,
    unsigned* __restrict__ ent)
{
    int g = blockIdx.x * 256 + threadIdx.x;      // [0, BN*GN)
    int b = g >> 13, i = g & (GN - 1);
    float mx = means2d[2 * g], my = means2d[2 * g + 1];
    float ca = conics[3 * g], cb = conics[3 * g + 1], cc = conics[3 * g + 2];
    float r = colors[3 * g], g2 = colors[3 * g + 1], b3 = colors[3 * g + 2];
    float op = opac[g];

    dat0[g] = make_float4(mx, my, ca, cb);
    dat1[g] = make_float4(cc, op, r, g2);
    dat2[g] = b3;

    float s = (op > 0.f) ? (logf(255.0f * op) + 1e-4f) : -1.0f;
    if (s < 0.f) return;                          // alpha < 1/255 everywhere
    float det = fmaxf(ca * cc - cb * cb, 1e-12f);
    float dxm = sqrtf(2.f * s * cc / det) + 0.02f;
    float dym = sqrtf(2.f * s * ca / det) + 0.02f;
    // pixel centers x+0.5 inside [mx-dxm, mx+dxm]; +-1px conservative slack
    int x0 = (int)floorf(mx - dxm - 0.5f), x1 = (int)ceilf(mx + dxm - 0.5f);
    int y0 = (int)floorf(my - dym - 0.5f), y1 = (int)ceilf(my + dym - 0.5f);
    if (x1 < 0 || x0 > WN - 1 || y1 < 0 || y0 > HN - 1) return;
    x0 = max(x0, 0); x1 = min(x1, WN - 1);
    y0 = max(y0, 0); y1 = min(y1, HN - 1);
    int tx0 = x0 >> 3, tx1 = x1 >> 3, ty0 = y0 >> 3, ty1 = y1 >> 3;
    for (int ty = ty0; ty <= ty1; ++ty)
        for (int tx = tx0; tx <= tx1; ++tx) {
            int t = b * NTILE + ty * TDIM + tx;
            unsigned pos = atomicAdd(&cur[t], 1u);
            if (pos < CAP) ent[t * CAP + pos] = (unsigned)i;
        }
}

// ---------------------------------------------------------------------------
// Kernel 2: raster. 64 threads = 1 wave = one 8x8 tile. Load this tile's
// list (L~48), bitonic-sort u64 keys (depth_bits<<13|idx) in LDS == stable
// depth argsort restricted to the tile, stage records to LDS, then composite
// front-to-back with 4-wide ILP batches (exact reference semantics).
// No per-chunk scan: cull cost moved to binning (O(G*coverage) total).
// ---------------------------------------------------------------------------
__global__ __launch_bounds__(64) void pgr_raster(
    const float* __restrict__ depths, const float4* __restrict__ dat0,
    const float4* __restrict__ dat1, const float* __restrict__ dat2,
    const unsigned* __restrict__ cur, const unsigned* __restrict__ ent,
    float* __restrict__ out)
{
    const int b = blockIdx.z;
    const int t = b * NTILE + blockIdx.y * TDIM + blockIdx.x;
    const int tid = threadIdx.x;
    const int tx0 = blockIdx.x * 8, ty0 = blockIdx.y * 8;
    const int lx = tid & 7, ly = tid >> 3;
    const float px = tx0 + lx + 0.5f, py = ty0 + ly + 0.5f;
    const int bG = b * GN;

    __shared__ unsigned long long s_key[256];     // pow2-padded sort buffer
    __shared__ float4 s_d0[CAP], s_d1[CAP];
    __shared__ float s_d2[CAP];

    const int L = min((int)cur[t], CAP);

    // build keys
    for (int i = tid; i < L; i += 64) {
        unsigned idx = ent[t * CAP + i];
        unsigned db = __float_as_uint(depths[bG + (int)idx]);
        s_key[i] = ((unsigned long long)db << 13) | idx;
    }
    int P2 = 64; while (P2 < L) P2 <<= 1;
    for (int i = L + tid; i < P2; i += 64) s_key[i] = ~0ull;
    __syncthreads();

    // bitonic ascending (single-wave block: barriers are cheap)
    for (int k = 2; k <= P2; k <<= 1) {
        for (int j = k >> 1; j > 0; j >>= 1) {
            for (int i = tid; i < P2; i += 64) {
                int ixj = i ^ j;
                if (ixj > i) {
                    unsigned long long a = s_key[i], bb = s_key[ixj];
                    bool up = ((i & k) == 0);
                    if (up ? (a > bb) : (a < bb)) { s_key[i] = bb; s_key[ixj] = a; }
                }
            }
            __syncthreads();
        }
    }

    // stage records in depth order
    for (int i = tid; i < L; i += 64) {
        int q = bG + (int)(s_key[i] & (GN - 1));
        s_d0[i] = dat0[q];
        s_d1[i] = dat1[q];
        s_d2[i] = dat2[q];
    }
    __syncthreads();

    float accR = 0.f, accG = 0.f, accB = 0.f, T = 1.f;
    int count = 0;
    bool done = false;

    for (int i0 = 0; i0 < L; i0 += 4) {
        if (__all((int)done)) break;
        float alpha[4], colR[4], colG[4], colB[4];
        bool valid[4];
        // phase 1: independent loads + sigma + exp (ILP hides LDS/exp latency)
        #pragma unroll
        for (int k = 0; k < 4; ++k) {
            int idx = i0 + k;
            bool act = (idx < L) && !done;
            int ii = act ? idx : i0;               // clamped, discarded
            float4 d0 = s_d0[ii];
            float4 d1 = s_d1[ii];
            float dx = __fsub_rn(px, d0.x);
            float dy = __fsub_rn(py, d0.y);
            // sigma = 0.5*((a*dx)*dx + (c*dy)*dy) + (b*dx)*dy (numpy order)
            float t1 = __fmul_rn(__fmul_rn(d0.z, dx), dx);
            float t2 = __fmul_rn(__fmul_rn(d1.x, dy), dy);
            float sigma = __fadd_rn(__fmul_rn(0.5f, __fadd_rn(t1, t2)),
                                    __fmul_rn(__fmul_rn(d0.w, dx), dy));
            bool v = act && sigma >= 0.f && sigma <= 5.55f;  // e^-5.55 < 1/255
            float al = v ? fminf(__fmul_rn(d1.y, expf(-sigma)), 0.999f) : 0.f;
            valid[k] = v && (al >= ALPHA_T);
            alpha[k] = al;
            colR[k] = d1.z; colG[k] = d1.w; colB[k] = s_d2[ii];
        }
        // phase 2: serial front-to-back blend (exact reference semantics)
        #pragma unroll
        for (int k = 0; k < 4; ++k) {
            if (valid[k] && !done) {
                float al = alpha[k];
                if (T > EPS_T) {
                    float w = __fmul_rn(T, al);
                    accR += w * colR[k];
                    accG += w * colG[k];
                    accB += w * colB[k];
                }
                T = __fmul_rn(T, __fsub_rn(1.f, al));
                count++;
                if (count >= FRONT_K || T <= EPS_T) done = true;
            }
        }
    }

    int o = ((b * HN + (ty0 + ly)) * WN + (tx0 + lx)) * 3;
    out[o] = accR;
    out[o + 1] = accG;
    out[o + 2] = accB;     // bg == 0, so output is accum only
}

extern "C" void kernel_launch(void* const* d_in, const int* in_sizes, int n_in,
                              void* d_out, int out_size, void* d_ws, size_t ws_size,
                              hipStream_t stream) {
    const float* means2d = (const float*)d_in[0];
    const float* conics  = (const float*)d_in[1];
    const float* colors  = (const float*)d_in[2];
    const float* opac    = (const float*)d_in[3];
    const float* depths  = (const float*)d_in[4];
    float* out = (float*)d_out;

    const int BG = BN * GN;
    float4*   dat0 = (float4*)d_ws;                       // 256 KB
    float4*   dat1 = dat0 + BG;                           // 256 KB
    float*    dat2 = (float*)(dat1 + BG);                 //  64 KB
    unsigned* cur  = (unsigned*)(dat2 + BG);              //   8 KB
    unsigned* ent  = cur + BN * NTILE;                    // 1.5 MB

    hipMemsetAsync(cur, 0, BN * NTILE * sizeof(unsigned), stream);
    pgr_prep<<<BG / 256, 256, 0, stream>>>(means2d, conics, colors, opac,
                                           dat0, dat1, dat2, cur, ent);
    pgr_raster<<<dim3(TDIM, TDIM, BN), 64, 0, stream>>>(
        depths, dat0, dat1, dat2, cur, ent, out);
}

// Round 6
// 56.608 us; speedup vs baseline: 3.8189x; 1.0015x over previous
//
#include <hip/hip_runtime.h>
#include <math.h>

#define GN 8192
#define BN 2
#define HN 256
#define WN 256
#define FRONT_K 8
#define EPS_T 1e-8f
#define ALPHA_T (1.0f / 255.0f)
#define TDIM 32                 // 32x32 tiles of 8x8 px per batch
#define NTILE (TDIM * TDIM)
#define CAP 256                 // per-tile list capacity (mean ~50; r5: 192 overflowed)

// ---------------------------------------------------------------------------
// Kernel 0: clear per-tile counters. 8 KB — a captured hipMemsetAsync node
// cost 39 us/replay (r5 rocprof: fillBufferAligned, WRITE_SIZE=8KB); this
// kernel does it in ~2 us.
// ---------------------------------------------------------------------------
__global__ __launch_bounds__(256) void pgr_clear(unsigned* __restrict__ cur)
{
    cur[blockIdx.x * 256 + threadIdx.x] = 0u;
}

// ---------------------------------------------------------------------------
// Kernel 1: prep + binning. One thread per (batch, gaussian):
//  - repack SoA records (ORIGINAL order; no global sort needed)
//  - conservative bbox (alpha>=1/255 <=> sigma<=ln(255*op)) -> tile rect
//  - atomicAdd-append orig index to each covered tile's list (order-free:
//    the raster sorts each tiny list by (depth,idx) key deterministically)
// ---------------------------------------------------------------------------
__global__ __launch_bounds__(256) void pgr_prep(
    const float* __restrict__ means2d, const float* __restrict__ conics,
    const float* __restrict__ colors, const float* __restrict__ opac,
    float4* __restrict__ dat0, float4* __restrict__ dat1,
    float* __restrict__ dat2, unsigned* __restrict__ cur,
    unsigned* __restrict__ ent)
{
    int g = blockIdx.x * 256 + threadIdx.x;      // [0, BN*GN)
    int b = g >> 13, i = g & (GN - 1);
    float mx = means2d[2 * g], my = means2d[2 * g + 1];
    float ca = conics[3 * g], cb = conics[3 * g + 1], cc = conics[3 * g + 2];
    float r = colors[3 * g], g2 = colors[3 * g + 1], b3 = colors[3 * g + 2];
    float op = opac[g];

    dat0[g] = make_float4(mx, my, ca, cb);
    dat1[g] = make_float4(cc, op, r, g2);
    dat2[g] = b3;

    float s = (op > 0.f) ? (logf(255.0f * op) + 1e-4f) : -1.0f;
    if (s < 0.f) return;                          // alpha < 1/255 everywhere
    float det = fmaxf(ca * cc - cb * cb, 1e-12f);
    float dxm = sqrtf(2.f * s * cc / det) + 0.02f;
    float dym = sqrtf(2.f * s * ca / det) + 0.02f;
    // pixel centers x+0.5 inside [mx-dxm, mx+dxm]; +-1px conservative slack
    int x0 = (int)floorf(mx - dxm - 0.5f), x1 = (int)ceilf(mx + dxm - 0.5f);
    int y0 = (int)floorf(my - dym - 0.5f), y1 = (int)ceilf(my + dym - 0.5f);
    if (x1 < 0 || x0 > WN - 1 || y1 < 0 || y0 > HN - 1) return;
    x0 = max(x0, 0); x1 = min(x1, WN - 1);
    y0 = max(y0, 0); y1 = min(y1, HN - 1);
    int tx0 = x0 >> 3, tx1 = x1 >> 3, ty0 = y0 >> 3, ty1 = y1 >> 3;
    for (int ty = ty0; ty <= ty1; ++ty)
        for (int tx = tx0; tx <= tx1; ++tx) {
            int t = b * NTILE + ty * TDIM + tx;
            unsigned pos = atomicAdd(&cur[t], 1u);
            if (pos < CAP) ent[t * CAP + pos] = (unsigned)i;
        }
}

// ---------------------------------------------------------------------------
// Kernel 2: raster. 64 threads = 1 wave = one 8x8 tile. Load this tile's
// list (L~50), bitonic-sort u64 keys (depth_bits<<13|idx) in LDS == stable
// depth argsort restricted to the tile, stage records to LDS, then composite
// front-to-back with 4-wide ILP batches (exact reference semantics).
// ---------------------------------------------------------------------------
__global__ __launch_bounds__(64) void pgr_raster(
    const float* __restrict__ depths, const float4* __restrict__ dat0,
    const float4* __restrict__ dat1, const float* __restrict__ dat2,
    const unsigned* __restrict__ cur, const unsigned* __restrict__ ent,
    float* __restrict__ out)
{
    const int b = blockIdx.z;
    const int t = b * NTILE + blockIdx.y * TDIM + blockIdx.x;
    const int tid = threadIdx.x;
    const int tx0 = blockIdx.x * 8, ty0 = blockIdx.y * 8;
    const int lx = tid & 7, ly = tid >> 3;
    const float px = tx0 + lx + 0.5f, py = ty0 + ly + 0.5f;
    const int bG = b * GN;

    __shared__ unsigned long long s_key[CAP];     // pow2-padded sort buffer
    __shared__ float4 s_d0[CAP], s_d1[CAP];
    __shared__ float s_d2[CAP];

    const int L = min((int)cur[t], CAP);

    // build keys
    for (int i = tid; i < L; i += 64) {
        unsigned idx = ent[t * CAP + i];
        unsigned db = __float_as_uint(depths[bG + (int)idx]);
        s_key[i] = ((unsigned long long)db << 13) | idx;
    }
    int P2 = 64; while (P2 < L) P2 <<= 1;
    for (int i = L + tid; i < P2; i += 64) s_key[i] = ~0ull;
    __syncthreads();

    // bitonic ascending (single-wave block: barriers are cheap)
    for (int k = 2; k <= P2; k <<= 1) {
        for (int j = k >> 1; j > 0; j >>= 1) {
            for (int i = tid; i < P2; i += 64) {
                int ixj = i ^ j;
                if (ixj > i) {
                    unsigned long long a = s_key[i], bb = s_key[ixj];
                    bool up = ((i & k) == 0);
                    if (up ? (a > bb) : (a < bb)) { s_key[i] = bb; s_key[ixj] = a; }
                }
            }
            __syncthreads();
        }
    }

    // stage records in depth order
    for (int i = tid; i < L; i += 64) {
        int q = bG + (int)(s_key[i] & (GN - 1));
        s_d0[i] = dat0[q];
        s_d1[i] = dat1[q];
        s_d2[i] = dat2[q];
    }
    __syncthreads();

    float accR = 0.f, accG = 0.f, accB = 0.f, T = 1.f;
    int count = 0;
    bool done = false;

    for (int i0 = 0; i0 < L; i0 += 4) {
        if (__all((int)done)) break;
        float alpha[4], colR[4], colG[4], colB[4];
        bool valid[4];
        // phase 1: independent loads + sigma + exp (ILP hides LDS/exp latency)
        #pragma unroll
        for (int k = 0; k < 4; ++k) {
            int idx = i0 + k;
            bool act = (idx < L) && !done;
            int ii = act ? idx : i0;               // clamped, discarded
            float4 d0 = s_d0[ii];
            float4 d1 = s_d1[ii];
            float dx = __fsub_rn(px, d0.x);
            float dy = __fsub_rn(py, d0.y);
            // sigma = 0.5*((a*dx)*dx + (c*dy)*dy) + (b*dx)*dy (numpy order)
            float t1 = __fmul_rn(__fmul_rn(d0.z, dx), dx);
            float t2 = __fmul_rn(__fmul_rn(d1.x, dy), dy);
            float sigma = __fadd_rn(__fmul_rn(0.5f, __fadd_rn(t1, t2)),
                                    __fmul_rn(__fmul_rn(d0.w, dx), dy));
            bool v = act && sigma >= 0.f && sigma <= 5.55f;  // e^-5.55 < 1/255
            float al = v ? fminf(__fmul_rn(d1.y, expf(-sigma)), 0.999f) : 0.f;
            valid[k] = v && (al >= ALPHA_T);
            alpha[k] = al;
            colR[k] = d1.z; colG[k] = d1.w; colB[k] = s_d2[ii];
        }
        // phase 2: serial front-to-back blend (exact reference semantics)
        #pragma unroll
        for (int k = 0; k < 4; ++k) {
            if (valid[k] && !done) {
                float al = alpha[k];
                if (T > EPS_T) {
                    float w = __fmul_rn(T, al);
                    accR += w * colR[k];
                    accG += w * colG[k];
                    accB += w * colB[k];
                }
                T = __fmul_rn(T, __fsub_rn(1.f, al));
                count++;
                if (count >= FRONT_K || T <= EPS_T) done = true;
            }
        }
    }

    int o = ((b * HN + (ty0 + ly)) * WN + (tx0 + lx)) * 3;
    out[o] = accR;
    out[o + 1] = accG;
    out[o + 2] = accB;     // bg == 0, so output is accum only
}

extern "C" void kernel_launch(void* const* d_in, const int* in_sizes, int n_in,
                              void* d_out, int out_size, void* d_ws, size_t ws_size,
                              hipStream_t stream) {
    const float* means2d = (const float*)d_in[0];
    const float* conics  = (const float*)d_in[1];
    const float* colors  = (const float*)d_in[2];
    const float* opac    = (const float*)d_in[3];
    const float* depths  = (const float*)d_in[4];
    float* out = (float*)d_out;

    const int BG = BN * GN;
    float4*   dat0 = (float4*)d_ws;                       // 256 KB
    float4*   dat1 = dat0 + BG;                           // 256 KB
    float*    dat2 = (float*)(dat1 + BG);                 //  64 KB
    unsigned* cur  = (unsigned*)(dat2 + BG);              //   8 KB
    unsigned* ent  = cur + BN * NTILE;                    //   2 MB

    pgr_clear<<<(BN * NTILE) / 256, 256, 0, stream>>>(cur);
    pgr_prep<<<BG / 256, 256, 0, stream>>>(means2d, conics, colors, opac,
                                           dat0, dat1, dat2, cur, ent);
    pgr_raster<<<dim3(TDIM, TDIM, BN), 64, 0, stream>>>(
        depths, dat0, dat1, dat2, cur, ent, out);
}

// Round 7
// 49.607 us; speedup vs baseline: 4.3578x; 1.1411x over previous
//
#include <hip/hip_runtime.h>
#include <math.h>

#define GN 8192
#define BN 2
#define HN 256
#define WN 256
#define FRONT_K 8
#define EPS_T 1e-8f
#define ALPHA_T (1.0f / 255.0f)
#define TDIM 32                 // 32x32 tiles of 8x8 px per batch
#define NTILE (TDIM * TDIM)
#define CAP 256                 // per-tile list capacity (mean ~50)

// ---------------------------------------------------------------------------
// Kernel 0: clear per-tile counters (2048 u32). Tiny; a dedicated kernel
// (hipMemsetAsync nodes showed pathological replay cost in r5 profiling).
// ---------------------------------------------------------------------------
__global__ __launch_bounds__(64) void pgr_clear(unsigned* __restrict__ cur)
{
    cur[blockIdx.x * 64 + threadIdx.x] = 0u;
}

// ---------------------------------------------------------------------------
// Kernel 1: prep + binning. One thread per (batch, gaussian):
//  - repack SoA records (original order)
//  - conservative bbox (alpha>=1/255 <=> sigma<=ln(255*op)) -> tile rect
//  - atomicAdd-append orig index to covered tiles' lists (append order is
//    irrelevant: raster rank-sorts each list by (depth,idx) deterministically)
// r6 fix: 64-thread blocks x 256 -> all 256 CUs active (was 64 CUs).
// ---------------------------------------------------------------------------
__global__ __launch_bounds__(64) void pgr_prep(
    const float* __restrict__ means2d, const float* __restrict__ conics,
    const float* __restrict__ colors, const float* __restrict__ opac,
    float4* __restrict__ dat0, float4* __restrict__ dat1,
    float* __restrict__ dat2, unsigned* __restrict__ cur,
    unsigned* __restrict__ ent)
{
    int g = blockIdx.x * 64 + threadIdx.x;       // [0, BN*GN)
    int b = g >> 13, i = g & (GN - 1);
    float mx = means2d[2 * g], my = means2d[2 * g + 1];
    float ca = conics[3 * g], cb = conics[3 * g + 1], cc = conics[3 * g + 2];
    float r = colors[3 * g], g2 = colors[3 * g + 1], b3 = colors[3 * g + 2];
    float op = opac[g];

    dat0[g] = make_float4(mx, my, ca, cb);
    dat1[g] = make_float4(cc, op, r, g2);
    dat2[g] = b3;

    float s = (op > 0.f) ? (logf(255.0f * op) + 1e-4f) : -1.0f;
    if (s < 0.f) return;                          // alpha < 1/255 everywhere
    float det = fmaxf(ca * cc - cb * cb, 1e-12f);
    float dxm = sqrtf(2.f * s * cc / det) + 0.02f;
    float dym = sqrtf(2.f * s * ca / det) + 0.02f;
    // pixel centers x+0.5 inside [mx-dxm, mx+dxm]; +-1px conservative slack
    int x0 = (int)floorf(mx - dxm - 0.5f), x1 = (int)ceilf(mx + dxm - 0.5f);
    int y0 = (int)floorf(my - dym - 0.5f), y1 = (int)ceilf(my + dym - 0.5f);
    if (x1 < 0 || x0 > WN - 1 || y1 < 0 || y0 > HN - 1) return;
    x0 = max(x0, 0); x1 = min(x1, WN - 1);
    y0 = max(y0, 0); y1 = min(y1, HN - 1);
    int tx0 = x0 >> 3, tx1 = x1 >> 3, ty0 = y0 >> 3, ty1 = y1 >> 3;
    for (int ty = ty0; ty <= ty1; ++ty)
        for (int tx = tx0; tx <= tx1; ++tx) {
            int t = b * NTILE + ty * TDIM + tx;
            unsigned pos = atomicAdd(&cur[t], 1u);
            if (pos < CAP) ent[t * CAP + pos] = (unsigned)i;
        }
}

// rank of key k among s_key[0..L): broadcast LDS reads, no barriers, pipelined
__device__ __forceinline__ int rank_of(const unsigned long long* s_key,
                                       unsigned long long k, int L)
{
    int rank = 0, j = 0;
    for (; j + 4 <= L; j += 4) {
        unsigned long long k0 = s_key[j], k1 = s_key[j + 1];
        unsigned long long k2 = s_key[j + 2], k3 = s_key[j + 3];
        rank += (int)(k0 < k) + (int)(k1 < k) + (int)(k2 < k) + (int)(k3 < k);
    }
    for (; j < L; ++j) rank += (int)(s_key[j] < k);
    return rank;
}

// ---------------------------------------------------------------------------
// Kernel 2: raster. 64 threads = 1 wave = one 8x8 tile.
// r6 rewrite: all-pairs RANK sort replaces the 21-barrier bitonic. Lane tid
// speculatively prefetches list entry tid's depth + full record (index masked
// &8191 -> always in-bounds, overlaps the cur[t] load), computes rank =
// #{smaller keys} via broadcast LDS reads, scatters record to LDS slot rank
// == exact stable (depth,idx) order. Composite in 8-wide ILP batches.
// ---------------------------------------------------------------------------
__global__ __launch_bounds__(64) void pgr_raster(
    const float* __restrict__ depths, const float4* __restrict__ dat0,
    const float4* __restrict__ dat1, const float* __restrict__ dat2,
    const unsigned* __restrict__ cur, const unsigned* __restrict__ ent,
    float* __restrict__ out)
{
    const int b = blockIdx.z;
    const int t = b * NTILE + blockIdx.y * TDIM + blockIdx.x;
    const int tid = threadIdx.x;
    const int tx0 = blockIdx.x * 8, ty0 = blockIdx.y * 8;
    const int lx = tid & 7, ly = tid >> 3;
    const float px = tx0 + lx + 0.5f, py = ty0 + ly + 0.5f;
    const int bG = b * GN;

    __shared__ unsigned long long s_key[CAP];
    __shared__ float4 s_d0[CAP], s_d1[CAP];
    __shared__ float s_d2[CAP];

    // speculative prefetch of entry `tid` (masked index: always in-bounds)
    unsigned eRaw = ent[t * CAP + tid];
    int e = (int)(eRaw & (GN - 1));
    int q = bG + e;
    float myd = depths[q];
    float4 r0 = dat0[q];
    float4 r1 = dat1[q];
    float r2 = dat2[q];
    const int L = min((int)cur[t], CAP);

    unsigned long long myk =
        ((unsigned long long)__float_as_uint(myd) << 13) | (unsigned)e;
    if (tid < L) s_key[tid] = myk;
    for (int i = 64 + tid; i < L; i += 64) {       // rare: L > 64
        int ei = (int)(ent[t * CAP + i] & (GN - 1));
        s_key[i] = ((unsigned long long)__float_as_uint(depths[bG + ei]) << 13)
                   | (unsigned)ei;
    }
    __syncthreads();

    if (tid < L) {
        int rank = rank_of(s_key, myk, L);
        s_d0[rank] = r0; s_d1[rank] = r1; s_d2[rank] = r2;
    }
    for (int i = 64 + tid; i < L; i += 64) {       // rare: L > 64
        unsigned long long k = s_key[i];
        int rank = rank_of(s_key, k, L);
        int qq = bG + (int)(k & (GN - 1));
        s_d0[rank] = dat0[qq]; s_d1[rank] = dat1[qq]; s_d2[rank] = dat2[qq];
    }
    __syncthreads();

    float accR = 0.f, accG = 0.f, accB = 0.f, T = 1.f;
    int count = 0;
    bool done = false;

    for (int i0 = 0; i0 < L; i0 += 8) {
        if (__all((int)done)) break;
        float alpha[8], colR[8], colG[8], colB[8];
        bool valid[8];
        // phase 1: 8 independent loads + sigma + exp (ILP hides LDS/exp latency)
        #pragma unroll
        for (int k = 0; k < 8; ++k) {
            int idx = i0 + k;
            bool act = (idx < L) && !done;
            int ii = act ? idx : i0;               // clamped, discarded
            float4 d0 = s_d0[ii];
            float4 d1 = s_d1[ii];
            float dx = __fsub_rn(px, d0.x);
            float dy = __fsub_rn(py, d0.y);
            // sigma = 0.5*((a*dx)*dx + (c*dy)*dy) + (b*dx)*dy (numpy order)
            float t1 = __fmul_rn(__fmul_rn(d0.z, dx), dx);
            float t2 = __fmul_rn(__fmul_rn(d1.x, dy), dy);
            float sigma = __fadd_rn(__fmul_rn(0.5f, __fadd_rn(t1, t2)),
                                    __fmul_rn(__fmul_rn(d0.w, dx), dy));
            bool v = act && sigma >= 0.f && sigma <= 5.55f;  // e^-5.55 < 1/255
            float al = v ? fminf(__fmul_rn(d1.y, expf(-sigma)), 0.999f) : 0.f;
            valid[k] = v && (al >= ALPHA_T);
            alpha[k] = al;
            colR[k] = d1.z; colG[k] = d1.w; colB[k] = s_d2[ii];
        }
        // phase 2: serial front-to-back blend (exact reference semantics)
        #pragma unroll
        for (int k = 0; k < 8; ++k) {
            if (valid[k] && !done) {
                float al = alpha[k];
                if (T > EPS_T) {
                    float w = __fmul_rn(T, al);
                    accR += w * colR[k];
                    accG += w * colG[k];
                    accB += w * colB[k];
                }
                T = __fmul_rn(T, __fsub_rn(1.f, al));
                count++;
                if (count >= FRONT_K || T <= EPS_T) done = true;
            }
        }
    }

    int o = ((b * HN + (ty0 + ly)) * WN + (tx0 + lx)) * 3;
    out[o] = accR;
    out[o + 1] = accG;
    out[o + 2] = accB;     // bg == 0, so output is accum only
}

extern "C" void kernel_launch(void* const* d_in, const int* in_sizes, int n_in,
                              void* d_out, int out_size, void* d_ws, size_t ws_size,
                              hipStream_t stream) {
    const float* means2d = (const float*)d_in[0];
    const float* conics  = (const float*)d_in[1];
    const float* colors  = (const float*)d_in[2];
    const float* opac    = (const float*)d_in[3];
    const float* depths  = (const float*)d_in[4];
    float* out = (float*)d_out;

    const int BG = BN * GN;
    float4*   dat0 = (float4*)d_ws;                       // 256 KB
    float4*   dat1 = dat0 + BG;                           // 256 KB
    float*    dat2 = (float*)(dat1 + BG);                 //  64 KB
    unsigned* cur  = (unsigned*)(dat2 + BG);              //   8 KB
    unsigned* ent  = cur + BN * NTILE;                    //   2 MB

    pgr_clear<<<(BN * NTILE) / 64, 64, 0, stream>>>(cur);
    pgr_prep<<<BG / 64, 64, 0, stream>>>(means2d, conics, colors, opac,
                                         dat0, dat1, dat2, cur, ent);
    pgr_raster<<<dim3(TDIM, TDIM, BN), 64, 0, stream>>>(
        depths, dat0, dat1, dat2, cur, ent, out);
}